// Round 3
// baseline (227.731 us; speedup 1.0000x reference)
//
#include <hip/hip_runtime.h>

// 8-bit ripple-borrow subtractor on 0/1-valued float32 rows.
// Row layout: index 7 is LSB. Output = [diffs (N,8) ; borrow (N,1)] flat.

typedef float f32x4 __attribute__((ext_vector_type(4)));  // native vector: OK for nontemporal builtins

__device__ __forceinline__ void sub8_row(
    const f32x4& a0, const f32x4& a1, const f32x4& b0, const f32x4& b1,
    float bin, f32x4& d0, f32x4& d1, float& bout)
{
    float av[8] = {a0.x, a0.y, a0.z, a0.w, a1.x, a1.y, a1.z, a1.w};
    float bv[8] = {b0.x, b0.y, b0.z, b0.w, b1.x, b1.y, b1.z, b1.w};
    float dv[8];
    bool borrow = bin != 0.0f;
    // Ripple from LSB (index 7) to MSB (index 0). All values are 0/1,
    // so boolean evaluation is bit-exact vs the float-arithmetic ref.
    #pragma unroll
    for (int j = 7; j >= 0; --j) {
        bool ai = av[j] != 0.0f;
        bool bi = bv[j] != 0.0f;
        bool diff = (ai ^ bi) ^ borrow;
        bool na = !ai;
        borrow = (na && bi) || (na && borrow) || (bi && borrow);
        dv[j] = diff ? 1.0f : 0.0f;
    }
    d0 = (f32x4){dv[0], dv[1], dv[2], dv[3]};
    d1 = (f32x4){dv[4], dv[5], dv[6], dv[7]};
    bout = borrow ? 1.0f : 0.0f;
}

__global__ __launch_bounds__(256) void sub8_kernel(
    const f32x4* __restrict__ A4, const f32x4* __restrict__ B4,
    const float* __restrict__ Bin, f32x4* __restrict__ D4,
    float* __restrict__ Bout, int n)
{
    const int stride = gridDim.x * blockDim.x;
    int i = blockIdx.x * blockDim.x + threadIdx.x;
    // Unrolled-by-2 grid-stride: two independent row streams in flight.
    for (; i + stride < n; i += 2 * stride) {
        int j = i + stride;
        // Issue all 8 vector loads + 2 scalar loads before any compute.
        f32x4 a0 = A4[2 * i],     a1 = A4[2 * i + 1];
        f32x4 b0 = B4[2 * i],     b1 = B4[2 * i + 1];
        f32x4 c0 = A4[2 * j],     c1 = A4[2 * j + 1];
        f32x4 e0 = B4[2 * j],     e1 = B4[2 * j + 1];
        float  bin_i = Bin[i],    bin_j = Bin[j];

        f32x4 d0, d1, f0, f1;
        float bo_i, bo_j;
        sub8_row(a0, a1, b0, b1, bin_i, d0, d1, bo_i);
        sub8_row(c0, c1, e0, e1, bin_j, f0, f1, bo_j);

        __builtin_nontemporal_store(d0, &D4[2 * i]);
        __builtin_nontemporal_store(d1, &D4[2 * i + 1]);
        __builtin_nontemporal_store(f0, &D4[2 * j]);
        __builtin_nontemporal_store(f1, &D4[2 * j + 1]);
        __builtin_nontemporal_store(bo_i, &Bout[i]);
        __builtin_nontemporal_store(bo_j, &Bout[j]);
    }
    // Tail (not taken when n is a multiple of 2*stride).
    for (; i < n; i += stride) {
        f32x4 a0 = A4[2 * i], a1 = A4[2 * i + 1];
        f32x4 b0 = B4[2 * i], b1 = B4[2 * i + 1];
        float bin_i = Bin[i];
        f32x4 d0, d1;
        float bo_i;
        sub8_row(a0, a1, b0, b1, bin_i, d0, d1, bo_i);
        __builtin_nontemporal_store(d0, &D4[2 * i]);
        __builtin_nontemporal_store(d1, &D4[2 * i + 1]);
        __builtin_nontemporal_store(bo_i, &Bout[i]);
    }
}

extern "C" void kernel_launch(void* const* d_in, const int* in_sizes, int n_in,
                              void* d_out, int out_size, void* d_ws, size_t ws_size,
                              hipStream_t stream) {
    const float* A   = (const float*)d_in[0];
    const float* B   = (const float*)d_in[1];
    const float* Bin = (const float*)d_in[2];
    int n = in_sizes[0] / 8;          // number of rows

    float* D    = (float*)d_out;          // (N,8) diffs
    float* Bout = D + (size_t)n * 8;      // (N,1) borrow-out

    const int block = 256;
    int grid = (n + block - 1) / block;
    if (grid > 2048) grid = 2048;         // grid-stride (×2 unrolled) the rest

    sub8_kernel<<<grid, block, 0, stream>>>(
        (const f32x4*)A, (const f32x4*)B, Bin, (f32x4*)D, Bout, n);
}

// Round 4
// 190.466 us; speedup vs baseline: 1.1957x; 1.1957x over previous
//
#include <hip/hip_runtime.h>

// 8-bit ripple-borrow subtractor on 0/1-valued float32 rows.
// Row layout: index 7 is LSB. Output = [diffs (N,8) ; borrow (N,1)] flat.
// R4: unroll-2 grid-stride for MLP; PLAIN stores (nontemporal caused 1.4x
// write amplification by defeating L2 write-combining of the stride-32B
// interleaved store pattern — R3 post-mortem).

typedef float f32x4 __attribute__((ext_vector_type(4)));

__device__ __forceinline__ void sub8_row(
    const f32x4& a0, const f32x4& a1, const f32x4& b0, const f32x4& b1,
    float bin, f32x4& d0, f32x4& d1, float& bout)
{
    float av[8] = {a0.x, a0.y, a0.z, a0.w, a1.x, a1.y, a1.z, a1.w};
    float bv[8] = {b0.x, b0.y, b0.z, b0.w, b1.x, b1.y, b1.z, b1.w};
    float dv[8];
    bool borrow = bin != 0.0f;
    // Ripple from LSB (index 7) to MSB (index 0). All values are 0/1,
    // so boolean evaluation is bit-exact vs the float-arithmetic ref.
    #pragma unroll
    for (int j = 7; j >= 0; --j) {
        bool ai = av[j] != 0.0f;
        bool bi = bv[j] != 0.0f;
        bool diff = (ai ^ bi) ^ borrow;
        bool na = !ai;
        borrow = (na && bi) || (na && borrow) || (bi && borrow);
        dv[j] = diff ? 1.0f : 0.0f;
    }
    d0 = (f32x4){dv[0], dv[1], dv[2], dv[3]};
    d1 = (f32x4){dv[4], dv[5], dv[6], dv[7]};
    bout = borrow ? 1.0f : 0.0f;
}

__global__ __launch_bounds__(256) void sub8_kernel(
    const f32x4* __restrict__ A4, const f32x4* __restrict__ B4,
    const float* __restrict__ Bin, f32x4* __restrict__ D4,
    float* __restrict__ Bout, int n)
{
    const int stride = gridDim.x * blockDim.x;
    int i = blockIdx.x * blockDim.x + threadIdx.x;
    // Unrolled-by-2 grid-stride: two independent row streams in flight.
    for (; i + stride < n; i += 2 * stride) {
        int j = i + stride;
        // Issue all 8 vector loads + 2 scalar loads before any compute.
        f32x4 a0 = A4[2 * i],     a1 = A4[2 * i + 1];
        f32x4 b0 = B4[2 * i],     b1 = B4[2 * i + 1];
        f32x4 c0 = A4[2 * j],     c1 = A4[2 * j + 1];
        f32x4 e0 = B4[2 * j],     e1 = B4[2 * j + 1];
        float  bin_i = Bin[i],    bin_j = Bin[j];

        f32x4 d0, d1, f0, f1;
        float bo_i, bo_j;
        sub8_row(a0, a1, b0, b1, bin_i, d0, d1, bo_i);
        sub8_row(c0, c1, e0, e1, bin_j, f0, f1, bo_j);

        D4[2 * i]     = d0;
        D4[2 * i + 1] = d1;
        D4[2 * j]     = f0;
        D4[2 * j + 1] = f1;
        Bout[i] = bo_i;
        Bout[j] = bo_j;
    }
    // Tail (not taken when n is a multiple of 2*stride).
    for (; i < n; i += stride) {
        f32x4 a0 = A4[2 * i], a1 = A4[2 * i + 1];
        f32x4 b0 = B4[2 * i], b1 = B4[2 * i + 1];
        float bin_i = Bin[i];
        f32x4 d0, d1;
        float bo_i;
        sub8_row(a0, a1, b0, b1, bin_i, d0, d1, bo_i);
        D4[2 * i]     = d0;
        D4[2 * i + 1] = d1;
        Bout[i] = bo_i;
    }
}

extern "C" void kernel_launch(void* const* d_in, const int* in_sizes, int n_in,
                              void* d_out, int out_size, void* d_ws, size_t ws_size,
                              hipStream_t stream) {
    const float* A   = (const float*)d_in[0];
    const float* B   = (const float*)d_in[1];
    const float* Bin = (const float*)d_in[2];
    int n = in_sizes[0] / 8;          // number of rows

    float* D    = (float*)d_out;          // (N,8) diffs
    float* Bout = D + (size_t)n * 8;      // (N,1) borrow-out

    const int block = 256;
    int grid = (n + block - 1) / block;
    if (grid > 2048) grid = 2048;         // grid-stride (×2 unrolled) the rest

    sub8_kernel<<<grid, block, 0, stream>>>(
        (const f32x4*)A, (const f32x4*)B, Bin, (f32x4*)D, Bout, n);
}

// Round 5
// 177.855 us; speedup vs baseline: 1.2804x; 1.0709x over previous
//
#include <hip/hip_runtime.h>

// 8-bit ripple-borrow subtractor on 0/1-valued float32 rows. Index 7 = LSB.
// Output = [diffs (N,8) ; borrow (N,1)] flat.
//
// R5: carry-select over lane pairs. Each row (32 B) is split across an
// even/odd lane pair so every global load/store is 16 B/lane CONTIGUOUS
// (previous one-row-per-thread layout had 32 B lane stride -> every memory
// instruction touched its span at half density; stuck at ~3 TB/s).
// Odd lane = LSB half (indices 4-7), even lane = MSB half (0-3). Both lanes
// compute their 4-bit ripple for borrow-in=0 and =1; odd lane resolves with
// Bin and ships its borrow-out to the even lane via one shfl_xor(1).

typedef float f32x4 __attribute__((ext_vector_type(4)));

__device__ __forceinline__ void half_ripple(const f32x4 a, const f32x4 b, bool bin,
                                            f32x4& d, bool& bout)
{
    float av[4] = {a.x, a.y, a.z, a.w};
    float bv[4] = {b.x, b.y, b.z, b.w};
    float dv[4];
    bool borrow = bin;
    // Ripple within the half: local index 3 is the less-significant end.
    #pragma unroll
    for (int j = 3; j >= 0; --j) {
        bool ai = av[j] != 0.0f;
        bool bi = bv[j] != 0.0f;
        bool diff = (ai ^ bi) ^ borrow;
        bool na = !ai;
        borrow = (na && bi) || (na && borrow) || (bi && borrow);
        dv[j] = diff ? 1.0f : 0.0f;
    }
    d = (f32x4){dv[0], dv[1], dv[2], dv[3]};
    bout = borrow;
}

__global__ __launch_bounds__(256) void sub8_kernel(
    const f32x4* __restrict__ A4, const f32x4* __restrict__ B4,
    const float* __restrict__ Bin, f32x4* __restrict__ D4,
    float* __restrict__ Bout, int n2 /* = 2*N half-rows */)
{
    const int stride = gridDim.x * blockDim.x;
    for (int t = blockIdx.x * blockDim.x + threadIdx.x; t < n2; t += stride) {
        const int  r   = t >> 1;        // row
        const bool odd = (t & 1) != 0;  // odd lane = LSB half

        f32x4 a = A4[t];                // contiguous 16 B/lane
        f32x4 b = B4[t];
        float binf = Bin[r];            // pair-shared address (L1 broadcast)

        f32x4 d0, d1;
        bool bo0, bo1;
        half_ripple(a, b, false, d0, bo0);
        half_ripple(a, b, true,  d1, bo1);

        // Odd lane: actual borrow-in from Bin; its borrow-out feeds partner.
        bool bin_low   = binf != 0.0f;
        bool bout_low  = bin_low ? bo1 : bo0;            // valid on odd lanes
        unsigned x     = __shfl_xor((unsigned)bout_low, 1);
        bool myborrow  = odd ? bin_low : (x != 0);

        f32x4 d = myborrow ? d1 : d0;
        D4[t] = d;                       // contiguous 16 B/lane

        if (!odd) {                      // even lane holds the final (MSB) borrow
            bool bfin = myborrow ? bo1 : bo0;
            Bout[r] = bfin ? 1.0f : 0.0f;
        }
    }
}

extern "C" void kernel_launch(void* const* d_in, const int* in_sizes, int n_in,
                              void* d_out, int out_size, void* d_ws, size_t ws_size,
                              hipStream_t stream) {
    const float* A   = (const float*)d_in[0];
    const float* B   = (const float*)d_in[1];
    const float* Bin = (const float*)d_in[2];
    int n  = in_sizes[0] / 8;             // rows
    int n2 = n * 2;                       // half-rows (one per thread)

    float* D    = (float*)d_out;          // (N,8) diffs
    float* Bout = D + (size_t)n * 8;      // (N,1) borrow-out

    const int block = 256;
    int grid = (n2 + block - 1) / block;
    if (grid > 2048) grid = 2048;         // grid-stride the rest

    sub8_kernel<<<grid, block, 0, stream>>>(
        (const f32x4*)A, (const f32x4*)B, Bin, (f32x4*)D, Bout, n2);
}

// Round 6
// 154.347 us; speedup vs baseline: 1.4755x; 1.1523x over previous
//
#include <hip/hip_runtime.h>

// 8-bit ripple-borrow subtractor on 0/1-valued float32 rows. Index 7 = LSB.
// Output = [diffs (N,8) ; borrow (N,1)] flat.
//
// R6: (a) full grid, one half-row per thread, NO grid-stride loop — R1..R5
// all capped at 2048 blocks and OccupancyPercent sat at 57-65% (static
// packing needs exactly 8 resident blocks/CU; imbalance starves CUs).
// Short-lived blocks keep CUs saturated by continuous dispatch.
// (b) pure bitwise compute on the 0x3F800000 bit-patterns: for v in
// {0.0f,1.0f}, XOR/AND/OR on the raw words implement the boolean algebra
// exactly and the result words ARE the correct floats. Bin/Bout used raw.
// Keeps R5's carry-select lane-pair layout (contiguous 16 B/lane).

typedef unsigned int u32;
typedef u32 u32x4 __attribute__((ext_vector_type(4)));
#define FONE 0x3F800000u  // bit pattern of 1.0f

__global__ __launch_bounds__(256) void sub8_kernel(
    const u32x4* __restrict__ A4, const u32x4* __restrict__ B4,
    const u32* __restrict__ Bin, u32x4* __restrict__ D4,
    u32* __restrict__ Bout, int n2 /* = 2*N half-rows */)
{
    int t = blockIdx.x * blockDim.x + threadIdx.x;
    if (t >= n2) return;
    const bool odd = (t & 1) != 0;  // odd lane = LSB half (indices 4-7)
    const int  r   = t >> 1;        // row

    u32x4 a = A4[t];                // contiguous 16 B/lane
    u32x4 b = B4[t];
    u32 binw = Bin[r];              // 0 or FONE (raw borrow-in word)

    // Dual 4-bit ripple (carry-select), bitwise on {0, FONE} words.
    // generate g = ~a & b, propagate p = ~a | b  (since (na&c)|(b&c) = (na|b)&c)
    u32 av[4] = {a.x, a.y, a.z, a.w};
    u32 bv[4] = {b.x, b.y, b.z, b.w};
    u32 d0v[4], d1v[4];
    u32 bor0 = 0u, bor1 = FONE;     // borrow-in = 0 / 1 hypotheses
    #pragma unroll
    for (int j = 3; j >= 0; --j) { // local index 3 = less-significant end
        u32 na = av[j] ^ FONE;
        u32 x  = av[j] ^ bv[j];
        u32 g  = na & bv[j];
        u32 p  = na | bv[j];
        d0v[j] = x ^ bor0;
        d1v[j] = x ^ bor1;
        bor0 = g | (p & bor0);
        bor1 = g | (p & bor1);
    }

    // Odd lane resolves with Bin; ships its borrow-out to the even lane.
    u32 bout_low = binw ? bor1 : bor0;            // valid on odd lanes
    u32 xs = __shfl_xor(bout_low, 1);
    u32 myborrow = odd ? binw : xs;               // 0 or FONE

    u32x4 d = myborrow ? (u32x4){d1v[0], d1v[1], d1v[2], d1v[3]}
                       : (u32x4){d0v[0], d0v[1], d0v[2], d0v[3]};
    D4[t] = d;                      // contiguous 16 B/lane

    if (!odd)                       // even lane holds the final (MSB) borrow
        Bout[r] = myborrow ? bor1 : bor0;
}

extern "C" void kernel_launch(void* const* d_in, const int* in_sizes, int n_in,
                              void* d_out, int out_size, void* d_ws, size_t ws_size,
                              hipStream_t stream) {
    const u32* A   = (const u32*)d_in[0];
    const u32* B   = (const u32*)d_in[1];
    const u32* Bin = (const u32*)d_in[2];
    int n  = in_sizes[0] / 8;             // rows
    int n2 = n * 2;                       // half-rows (one per thread)

    u32* D    = (u32*)d_out;              // (N,8) diffs
    u32* Bout = D + (size_t)n * 8;        // (N,1) borrow-out

    const int block = 256;
    int grid = (n2 + block - 1) / block;  // full grid, no cap (65536 blocks)

    sub8_kernel<<<grid, block, 0, stream>>>(
        (const u32x4*)A, (const u32x4*)B, Bin, (u32x4*)D, Bout, n2);
}